// Round 15
// baseline (205.566 us; speedup 1.0000x reference)
//
#include <hip/hip_runtime.h>
#include <stdint.h>

#define S_LEN 4096
#define KEEP_P 0.991f

typedef __attribute__((ext_vector_type(8)))  short bf16x8;
typedef __attribute__((ext_vector_type(16))) float f32x16;
typedef __attribute__((ext_vector_type(4)))  int   i32x4;
typedef __attribute__((ext_vector_type(2)))  int   i32x2;

// keep  <=>  (o0^o1) < KEEP_TH  (integer form of u<0.991f; f32(0.991)=8313111*2^-23,
// u = m*2^-23 exactly (Sterbenz), so u<0.991 <=> m<8313111 <=> bits < 8313111<<9)
static constexpr uint32_t KEEP_TH = 4256312832u;        // 8313111 << 9

// rotl(x,r) as ONE v_alignbit_b32 (shift = 32-r), single-inst asm expression the
// scheduler can interleave (r13-proven).
#define TFR_AB(sh) { v0 += v1; uint32_t d_;                                  \
  asm("v_alignbit_b32 %0, %1, %1, " #sh : "=v"(d_) : "v"(v1));               \
  v1 = d_ ^ v0; }

// Exact JAX threefry2x32 for key = jax.random.key(1) -> (k0,k1)=(0,1)
// Round shifts r=13,15,26,6 -> alignbit 19,17,6,26 ; r=17,29,16,24 -> 15,3,16,8.
__device__ __forceinline__ void threefry(uint32_t x0, uint32_t x1,
                                         uint32_t& o0, uint32_t& o1) {
  const uint32_t k0 = 0u, k1 = 1u, k2 = 0x1BD11BDBu;
  uint32_t v0 = x0 + k0, v1 = x1 + k1;
  TFR_AB(19) TFR_AB(17) TFR_AB(6) TFR_AB(26)     // rounds 1-4
  v0 += k1; v1 += k2 + 1u;
  TFR_AB(15) TFR_AB(3) TFR_AB(16) TFR_AB(8)      // rounds 5-8
  v0 += k2; v1 += k0 + 2u;
  TFR_AB(19) TFR_AB(17) TFR_AB(6) TFR_AB(26)     // rounds 9-12
  v0 += k0; v1 += k1 + 3u;
  TFR_AB(15) TFR_AB(3) TFR_AB(16) TFR_AB(8)      // rounds 13-16
  v0 += k1; v1 += k2 + 4u;
  TFR_AB(19) TFR_AB(17) TFR_AB(6) TFR_AB(26)     // rounds 17-20
  v0 += k2; v1 += k0 + 5u;
  o0 = v0; o1 = v1;
}

__device__ __forceinline__ uint32_t f2u(float f){ union{float f;uint32_t u;}x; x.f=f; return x.u; }
__device__ __forceinline__ float u2f(uint32_t u){ union{uint32_t u;float f;}x; x.u=u; return x.f; }

// One block = 768 threads = 12 waves: waves 0-7 attn (r13 math, unchanged),
// waves 8-11 produce this block's dropout-mask words into an LDS double buffer.
// Both roles execute EXACTLY 67 __syncthreads (2 prologue + 64 loop + 1 epilogue)
// -> deadlock impossible (single-block sync only). Producer writes mbuf[(t+1)&1]
// during iter t; consumer reads mbuf[t&1] after iter t's first barrier.
__global__ __launch_bounds__(768, 3)
void fused_attn(const float* __restrict__ Qg, const float* __restrict__ Kg,
                const float* __restrict__ Vg, const float* __restrict__ Sdiv,
                float* __restrict__ Out)
{
  __shared__ __align__(16) unsigned char smem[49152]; // khi 16K | klo 16K | v 16K
  __shared__ float sm_ml[2][3][2][32];
  __shared__ uint32_t mbuf[2][64][4];                 // [parity][row][kv-word]

  const int t = threadIdx.x;

  const int blk = blockIdx.x;
  const int xcd = blk & 7;
  const int b   = xcd >> 1;
  const int qblock = ((xcd & 1) << 5) | (blk >> 3);  // 0..63
  const int qt  = qblock * 64;

  if (t >= 512) {
    // ---------------- mask producer role (waves 8-11, 256 lanes) ----------------
    const int p    = t - 512;       // 0..255
    const int row  = p >> 2;        // 0..63 (local q-row)
    const int word = p & 3;         // kv-word within 128-tile
    const uint32_t fb0 = (((uint32_t)b * 4096u + (uint32_t)(qt + row)) << 12)
                       + ((uint32_t)word << 5);

    // prologue: tile 0 into mbuf[0], then match attn's 2 prologue barriers
    {
      uint32_t wlo = 0u, whi = 0u;
#pragma unroll
      for (uint32_t j = 0; j < 16u; ++j) {
        uint32_t a0, a1, b0, b1;
        threefry(0u, fb0 + j,        a0, a1);
        threefry(0u, fb0 + j + 16u,  b0, b1);
        wlo |= (uint32_t)((a0 ^ a1) < KEEP_TH) << j;
        whi |= (uint32_t)((b0 ^ b1) < KEEP_TH) << j;
      }
      mbuf[0][row][word] = wlo | (whi << 16);
    }
    __syncthreads();   // matches attn prologue barrier 1
    __syncthreads();   // matches attn prologue barrier 2

#pragma unroll 1
    for (int tt = 0; tt < 32; ++tt) {
      if (tt < 31) {
        const uint32_t fb = fb0 + (uint32_t)((tt + 1) << 7);
        uint32_t wlo = 0u, whi = 0u;
#pragma unroll
        for (uint32_t j = 0; j < 16u; ++j) {
          uint32_t a0, a1, b0, b1;
          threefry(0u, fb + j,        a0, a1);
          threefry(0u, fb + j + 16u,  b0, b1);
          wlo |= (uint32_t)((a0 ^ a1) < KEEP_TH) << j;
          whi |= (uint32_t)((b0 ^ b1) < KEEP_TH) << j;
        }
        mbuf[(tt + 1) & 1][row][word] = wlo | (whi << 16);
      }
      __syncthreads();   // matches attn loop barrier A
      __syncthreads();   // matches attn loop barrier B
    }
    __syncthreads();     // matches attn epilogue barrier
    return;
  }

  // ---------------- attention role (waves 0-7) ----------------
  char* khiB = (char*)smem;
  char* kloB = (char*)smem + 16384;
  char* vtsB = (char*)smem + 32768;
  float* smf = (float*)smem;   // epilogue scratch (reuse)

  const int lane = t & 63;
  const int w    = t >> 6;     // wave 0..7
  const int wq   = w >> 2;     // q-group 0..1 (32 q each)
  const int h    = w & 3;      // kv quarter 0..3 (32 kv each)
  const int l31  = lane & 31;
  const int hi5  = lane >> 5;

  const float inv_s = 1.0f / Sdiv[0];
  const float* Qp = Qg + (size_t)b * S_LEN * 64;
  const float* Kp = Kg + (size_t)b * S_LEN * 64;
  const float* Vp = Vg + (size_t)b * S_LEN * 64;

  // ---- stage Q (64 rows) hi/lo into khi/klo rows 0..63 (plain layout + XOR swizzle) ----
#pragma unroll
  for (int rr = 0; rr < 2; ++rr) {
    int row = rr * 32 + (t >> 4);
    int c   = (t & 15) * 4;
    float4 q4 = *(const float4*)(Qp + (size_t)(qt + row) * 64 + c);
    uint32_t u0=f2u(q4.x),u1=f2u(q4.y),u2=f2u(q4.z),u3=f2u(q4.w);
    uint32_t h01=(u1&0xFFFF0000u)|(u0>>16), h23=(u3&0xFFFF0000u)|(u2>>16);
    uint32_t l0=f2u(q4.x-u2f(u0&0xFFFF0000u)), l1=f2u(q4.y-u2f(u1&0xFFFF0000u));
    uint32_t l2=f2u(q4.z-u2f(u2&0xFFFF0000u)), l3=f2u(q4.w-u2f(u3&0xFFFF0000u));
    uint32_t lo01=(l1&0xFFFF0000u)|(l0>>16), lo23=(l3&0xFFFF0000u)|(l2>>16);
    uint32_t off = ((uint32_t)(row*128 + c*2)) ^ ((uint32_t)((row&7)<<4));
    *(i32x2*)(khiB + off) = i32x2{(int)h01,(int)h23};
    *(i32x2*)(kloB + off) = i32x2{(int)lo01,(int)lo23};
  }
  __syncthreads();                               // barrier 1
  bf16x8 qhi[4], qlo[4];
  {
    int qrow = wq * 32 + l31;
#pragma unroll
    for (int kc = 0; kc < 4; ++kc) {
      uint32_t off = ((uint32_t)(qrow*128 + kc*32 + hi5*16)) ^ ((uint32_t)((qrow&7)<<4));
      qhi[kc] = *(const bf16x8*)(khiB + off);
      qlo[kc] = *(const bf16x8*)(kloB + off);
    }
  }
  __syncthreads();                               // barrier 2

  f32x16 o0, o1;
#pragma unroll
  for (int i = 0; i < 16; ++i) { o0[i] = 0.f; o1[i] = 0.f; }
  float m = -INFINITY, lsum = 0.f;

  const int rowk = h * 32 + l31;

  union PU { i32x4 i; bf16x8 bv; };

  for (int kt0 = 0; kt0 < S_LEN; kt0 += 128) {
    // ---- stage K (hi/lo, plain+swizzle) and V (plain row-major bf16 [128][64]) ----
#pragma unroll
    for (int rr = 0; rr < 4; ++rr) {
      int row = rr * 32 + (t >> 4);
      int c   = (t & 15) * 4;
      float4 k4 = *(const float4*)(Kp + (size_t)(kt0 + row) * 64 + c);
      uint32_t u0=f2u(k4.x),u1=f2u(k4.y),u2=f2u(k4.z),u3=f2u(k4.w);
      uint32_t h01=(u1&0xFFFF0000u)|(u0>>16), h23=(u3&0xFFFF0000u)|(u2>>16);
      uint32_t l0=f2u(k4.x-u2f(u0&0xFFFF0000u)), l1=f2u(k4.y-u2f(u1&0xFFFF0000u));
      uint32_t l2=f2u(k4.z-u2f(u2&0xFFFF0000u)), l3=f2u(k4.w-u2f(u3&0xFFFF0000u));
      uint32_t lo01=(l1&0xFFFF0000u)|(l0>>16), lo23=(l3&0xFFFF0000u)|(l2>>16);
      uint32_t off = ((uint32_t)(row*128 + c*2)) ^ ((uint32_t)((row&7)<<4));
      *(i32x2*)(khiB + off) = i32x2{(int)h01,(int)h23};
      *(i32x2*)(kloB + off) = i32x2{(int)lo01,(int)lo23};

      float4 v4 = *(const float4*)(Vp + (size_t)(kt0 + row) * 64 + c);
      uint32_t vp01, vp23;
      asm("v_cvt_pk_bf16_f32 %0, %1, %2" : "=v"(vp01) : "v"(v4.x), "v"(v4.y));
      asm("v_cvt_pk_bf16_f32 %0, %1, %2" : "=v"(vp23) : "v"(v4.z), "v"(v4.w));
      *(i32x2*)(vtsB + (uint32_t)(row*128 + c*2)) = i32x2{(int)vp01,(int)vp23};
    }
    __syncthreads();                             // barrier A

    // ---- dropout mask word from the producer waves' LDS ring ----
    const uint32_t mw = mbuf[(kt0 >> 7) & 1][wq * 32 + l31][h];

    // ---- QK^T: S^T = K * Q^T, 3-pass split bf16 ----
    f32x16 acc;
#pragma unroll
    for (int i = 0; i < 16; ++i) acc[i] = 0.f;
    bf16x8 kfrag[4];
    const uint32_t kswz = (uint32_t)((rowk&7)<<4);
#pragma unroll
    for (int kc = 0; kc < 4; ++kc) {
      uint32_t off = ((uint32_t)(rowk*128 + kc*32 + hi5*16)) ^ kswz;
      kfrag[kc] = *(const bf16x8*)(khiB + off);
    }
#pragma unroll
    for (int kc = 0; kc < 4; ++kc)
      acc = __builtin_amdgcn_mfma_f32_32x32x16_bf16(kfrag[kc], qhi[kc], acc, 0, 0, 0);
#pragma unroll
    for (int kc = 0; kc < 4; ++kc)
      acc = __builtin_amdgcn_mfma_f32_32x32x16_bf16(kfrag[kc], qlo[kc], acc, 0, 0, 0);
#pragma unroll
    for (int kc = 0; kc < 4; ++kc) {
      uint32_t off = ((uint32_t)(rowk*128 + kc*32 + hi5*16)) ^ kswz;
      kfrag[kc] = *(const bf16x8*)(kloB + off);
    }
#pragma unroll
    for (int kc = 0; kc < 4; ++kc)
      acc = __builtin_amdgcn_mfma_f32_32x32x16_bf16(kfrag[kc], qhi[kc], acc, 0, 0, 0);

    // ---- online softmax (lane-local: all 16 regs share q = l31) ----
    float z[16];
#pragma unroll
    for (int i = 0; i < 16; ++i) z[i] = acc[i] * inv_s;
    float tmax = z[0];
#pragma unroll
    for (int i = 1; i < 16; ++i) tmax = fmaxf(tmax, z[i]);
    tmax = fmaxf(tmax, __shfl_xor(tmax, 32));
    float mn = fmaxf(m, tmax);
    if (!__all(mn == m)) {
      float cr = __expf(m - mn);
      m = mn;
      lsum *= cr;
#pragma unroll
      for (int r = 0; r < 16; ++r) {
        int qr = (r & 3) + 8 * (r >> 2) + 4 * hi5;
        float cq = __shfl(cr, qr);
        o0[r] *= cq; o1[r] *= cq;
      }
    }
    float em[16];
#pragma unroll
    for (int r = 0; r < 16; ++r) {
      float e = __expf(z[r] - m);
      lsum += e;                                   // denominator: UNMASKED
      int bit = (r & 3) + 8 * (r >> 2) + 4 * hi5;  // kv-local index
      em[r] = ((mw >> bit) & 1u) ? e : 0.f;
    }

    // ---- P -> A-operand fragments (contiguous k = 8*hi5+j) via cvt_pk + shfl_xor(32) ----
    uint32_t cw[8];
#pragma unroll
    for (int i = 0; i < 8; ++i)
      asm("v_cvt_pk_bf16_f32 %0, %1, %2" : "=v"(cw[i]) : "v"(em[2*i]), "v"(em[2*i+1]));
    uint32_t sx[8];
#pragma unroll
    for (int i = 0; i < 8; ++i) sx[i] = (uint32_t)__shfl_xor((int)cw[i], 32);
    PU pf0, pf1;
    pf0.i = i32x4{ (int)(hi5 ? sx[2] : cw[0]),
                   (int)(hi5 ? sx[3] : cw[1]),
                   (int)(hi5 ? cw[2] : sx[0]),
                   (int)(hi5 ? cw[3] : sx[1]) };
    pf1.i = i32x4{ (int)(hi5 ? sx[6] : cw[4]),
                   (int)(hi5 ? sx[7] : cw[5]),
                   (int)(hi5 ? cw[6] : sx[4]),
                   (int)(hi5 ? cw[7] : sx[5]) };

    // ---- V B-fragments: scalar u16 gathers from row-major V tile ----
    PU vf00, vf01, vf10, vf11;
#pragma unroll
    for (int ks = 0; ks < 2; ++ks)
#pragma unroll
      for (int vb = 0; vb < 2; ++vb) {
        int wds[4];
#pragma unroll
        for (int jj = 0; jj < 4; ++jj) {
          int k0 = 32*h + 16*ks + 8*hi5 + 2*jj;
          uint32_t lo = *(const uint16_t*)(vtsB + k0*128     + (vb*32 + l31)*2);
          uint32_t hi = *(const uint16_t*)(vtsB + (k0+1)*128 + (vb*32 + l31)*2);
          wds[jj] = (int)(lo | (hi << 16));
        }
        PU tmp; tmp.i = i32x4{wds[0], wds[1], wds[2], wds[3]};
        if (ks == 0 && vb == 0) vf00 = tmp;
        else if (ks == 0 && vb == 1) vf01 = tmp;
        else if (ks == 1 && vb == 0) vf10 = tmp;
        else vf11 = tmp;
      }

    // ---- PV: O = P * V ----
    o0 = __builtin_amdgcn_mfma_f32_32x32x16_bf16(pf0.bv, vf00.bv, o0, 0, 0, 0);
    o0 = __builtin_amdgcn_mfma_f32_32x32x16_bf16(pf1.bv, vf10.bv, o0, 0, 0, 0);
    o1 = __builtin_amdgcn_mfma_f32_32x32x16_bf16(pf0.bv, vf01.bv, o1, 0, 0, 0);
    o1 = __builtin_amdgcn_mfma_f32_32x32x16_bf16(pf1.bv, vf11.bv, o1, 0, 0, 0);
    __syncthreads();                             // barrier B
  }

  // ---- merge the 4 kv-quarters per q-group ----
  lsum += __shfl_xor(lsum, 32);
  if (h > 0) {
    if (lane < 32) { sm_ml[wq][h-1][0][l31] = m; sm_ml[wq][h-1][1][l31] = lsum; }
    float* dst = smf + (size_t)(wq * 3 + (h - 1)) * 2048;
#pragma unroll
    for (int r = 0; r < 16; ++r) {
      int qr = (r & 3) + 8 * (r >> 2) + 4 * hi5;
      dst[qr * 64 + l31]      = o0[r];
      dst[qr * 64 + 32 + l31] = o1[r];
    }
  }
  __syncthreads();                               // epilogue barrier
  if (h == 0) {
#pragma unroll
    for (int hp = 1; hp < 4; ++hp) {
      float mp = sm_ml[wq][hp-1][0][l31];
      float lp = sm_ml[wq][hp-1][1][l31];
      float mm = fmaxf(m, mp);
      float ca = __expf(m - mm);
      float cb = __expf(mp - mm);
      lsum = lsum * ca + lp * cb;
      m = mm;
      const float* srcp = smf + (size_t)(wq * 3 + (hp - 1)) * 2048;
#pragma unroll
      for (int r = 0; r < 16; ++r) {
        int qr = (r & 3) + 8 * (r >> 2) + 4 * hi5;
        float caq = __shfl(ca, qr);
        float cbq = __shfl(cb, qr);
        o0[r] = o0[r] * caq + srcp[qr * 64 + l31] * cbq;
        o1[r] = o1[r] * caq + srcp[qr * 64 + 32 + l31] * cbq;
      }
    }
    float rinv = 1.0f / (lsum * KEEP_P);
    float* op = Out + ((size_t)b * S_LEN + (size_t)(qt + wq * 32)) * 64;
#pragma unroll
    for (int r = 0; r < 16; ++r) {
      int qr = (r & 3) + 8 * (r >> 2) + 4 * hi5;
      float rq = __shfl(rinv, qr);
      op[(size_t)qr * 64 + l31]      = o0[r] * rq;
      op[(size_t)qr * 64 + 32 + l31] = o1[r] * rq;
    }
  }
}

extern "C" void kernel_launch(void* const* d_in, const int* in_sizes, int n_in,
                              void* d_out, int out_size, void* d_ws, size_t ws_size,
                              hipStream_t stream) {
  (void)in_sizes; (void)n_in; (void)out_size; (void)d_ws; (void)ws_size;
  const float* q = (const float*)d_in[0];
  const float* k = (const float*)d_in[1];
  const float* v = (const float*)d_in[2];
  const float* s = (const float*)d_in[3];
  float* out = (float*)d_out;

  fused_attn<<<dim3(256), dim3(768), 0, stream>>>(q, k, v, s, out);
}

// Round 16
// 172.284 us; speedup vs baseline: 1.1932x; 1.1932x over previous
//
#include <hip/hip_runtime.h>
#include <stdint.h>

#define S_LEN 4096
#define KEEP_P 0.991f

typedef __attribute__((ext_vector_type(8)))  short bf16x8;
typedef __attribute__((ext_vector_type(16))) float f32x16;
typedef __attribute__((ext_vector_type(4)))  int   i32x4;
typedef __attribute__((ext_vector_type(2)))  int   i32x2;

static constexpr uint32_t TOTAL_N    = 4u * 4096u * 4096u;
static constexpr uint32_t MASK_WORDS = TOTAL_N / 32u;   // 8 MB bitmask
// keep  <=>  (o0^o1) < KEEP_TH  (integer form of u<0.991f; f32(0.991)=8313111*2^-23,
// u = m*2^-23 exactly (Sterbenz), so u<0.991 <=> m<8313111 <=> bits < 8313111<<9)
static constexpr uint32_t KEEP_TH = 4256312832u;        // 8313111 << 9

// rotl(x,r) as ONE v_alignbit_b32 (shift = 32-r), single-inst asm expression the
// scheduler can interleave (r13-proven: maskgen 129 -> ~107 us).
#define TFR_AB(sh) { v0 += v1; uint32_t d_;                                  \
  asm("v_alignbit_b32 %0, %1, %1, " #sh : "=v"(d_) : "v"(v1));               \
  v1 = d_ ^ v0; }

// Exact JAX threefry2x32 for key = jax.random.key(1) -> (k0,k1)=(0,1)
// Round shifts r=13,15,26,6 -> alignbit 19,17,6,26 ; r=17,29,16,24 -> 15,3,16,8.
__device__ __forceinline__ void threefry(uint32_t x0, uint32_t x1,
                                         uint32_t& o0, uint32_t& o1) {
  const uint32_t k0 = 0u, k1 = 1u, k2 = 0x1BD11BDBu;
  uint32_t v0 = x0 + k0, v1 = x1 + k1;
  TFR_AB(19) TFR_AB(17) TFR_AB(6) TFR_AB(26)     // rounds 1-4
  v0 += k1; v1 += k2 + 1u;
  TFR_AB(15) TFR_AB(3) TFR_AB(16) TFR_AB(8)      // rounds 5-8
  v0 += k2; v1 += k0 + 2u;
  TFR_AB(19) TFR_AB(17) TFR_AB(6) TFR_AB(26)     // rounds 9-12
  v0 += k0; v1 += k1 + 3u;
  TFR_AB(15) TFR_AB(3) TFR_AB(16) TFR_AB(8)      // rounds 13-16
  v0 += k1; v1 += k2 + 4u;
  TFR_AB(19) TFR_AB(17) TFR_AB(6) TFR_AB(26)     // rounds 17-20
  v0 += k2; v1 += k0 + 5u;
  o0 = v0; o1 = v1;
}

// jax_threefry_partitionable path: bits = o0^o1 of threefry(0, i)
__device__ __forceinline__ bool keep_partitionable(uint32_t i) {
  uint32_t o0, o1;
  threefry(0u, i, o0, o1);
  return (o0 ^ o1) < KEEP_TH;
}

// word-per-thread, 2 independent evals per iteration (bits j and j+16)
__global__ __launch_bounds__(256) void maskgen_kernel(uint32_t* __restrict__ mask) {
  uint32_t gid  = blockIdx.x * 256u + threadIdx.x;   // < MASK_WORDS
  uint32_t base = gid * 32u;
  uint32_t wlo = 0u, whi = 0u;
#pragma unroll
  for (uint32_t j = 0; j < 16u; ++j) {
    uint32_t a0, a1, b0, b1;
    threefry(0u, base + j,        a0, a1);
    threefry(0u, base + j + 16u,  b0, b1);
    wlo |= (uint32_t)((a0 ^ a1) < KEEP_TH) << j;
    whi |= (uint32_t)((b0 ^ b1) < KEEP_TH) << j;
  }
  mask[gid] = wlo | (whi << 16);
}

__device__ __forceinline__ uint32_t f2u(float f){ union{float f;uint32_t u;}x; x.f=f; return x.u; }
__device__ __forceinline__ float u2f(uint32_t u){ union{uint32_t u;float f;}x; x.u=u; return x.f; }

template<bool USE_WS>
__global__ __launch_bounds__(512, 2)
void attn_mfma(const float* __restrict__ Qg, const float* __restrict__ Kg,
               const float* __restrict__ Vg, const float* __restrict__ Sdiv,
               const uint32_t* __restrict__ Mask, float* __restrict__ Out)
{
  __shared__ __align__(16) unsigned char smem[49152]; // khi 16K | klo 16K | v 16K
  __shared__ float sm_ml[2][3][2][32];
  char* khiB = (char*)smem;
  char* kloB = (char*)smem + 16384;
  char* vtsB = (char*)smem + 32768;
  float* smf = (float*)smem;   // epilogue scratch (reuse)

  const int t    = threadIdx.x;
  const int lane = t & 63;
  const int w    = t >> 6;     // wave 0..7
  const int wq   = w >> 2;     // q-group 0..1 (32 q each)
  const int h    = w & 3;      // kv quarter 0..3 (32 kv each)
  const int l31  = lane & 31;
  const int hi5  = lane >> 5;

  const int blk = blockIdx.x;
  const int xcd = blk & 7;
  const int b   = xcd >> 1;
  const int qblock = ((xcd & 1) << 5) | (blk >> 3);  // 0..63
  const int qt  = qblock * 64;

  const float inv_s = 1.0f / Sdiv[0];
  const float* Qp = Qg + (size_t)b * S_LEN * 64;
  const float* Kp = Kg + (size_t)b * S_LEN * 64;
  const float* Vp = Vg + (size_t)b * S_LEN * 64;

  // ---- stage Q (64 rows) hi/lo into khi/klo rows 0..63 (plain layout + XOR swizzle) ----
#pragma unroll
  for (int rr = 0; rr < 2; ++rr) {
    int row = rr * 32 + (t >> 4);
    int c   = (t & 15) * 4;
    float4 q4 = *(const float4*)(Qp + (size_t)(qt + row) * 64 + c);
    uint32_t u0=f2u(q4.x),u1=f2u(q4.y),u2=f2u(q4.z),u3=f2u(q4.w);
    uint32_t h01=(u1&0xFFFF0000u)|(u0>>16), h23=(u3&0xFFFF0000u)|(u2>>16);
    uint32_t l0=f2u(q4.x-u2f(u0&0xFFFF0000u)), l1=f2u(q4.y-u2f(u1&0xFFFF0000u));
    uint32_t l2=f2u(q4.z-u2f(u2&0xFFFF0000u)), l3=f2u(q4.w-u2f(u3&0xFFFF0000u));
    uint32_t lo01=(l1&0xFFFF0000u)|(l0>>16), lo23=(l3&0xFFFF0000u)|(l2>>16);
    uint32_t off = ((uint32_t)(row*128 + c*2)) ^ ((uint32_t)((row&7)<<4));
    *(i32x2*)(khiB + off) = i32x2{(int)h01,(int)h23};
    *(i32x2*)(kloB + off) = i32x2{(int)lo01,(int)lo23};
  }
  __syncthreads();
  bf16x8 qhi[4], qlo[4];
  {
    int qrow = wq * 32 + l31;
#pragma unroll
    for (int kc = 0; kc < 4; ++kc) {
      uint32_t off = ((uint32_t)(qrow*128 + kc*32 + hi5*16)) ^ ((uint32_t)((qrow&7)<<4));
      qhi[kc] = *(const bf16x8*)(khiB + off);
      qlo[kc] = *(const bf16x8*)(kloB + off);
    }
  }
  __syncthreads();

  f32x16 o0, o1;
#pragma unroll
  for (int i = 0; i < 16; ++i) { o0[i] = 0.f; o1[i] = 0.f; }
  float m = -INFINITY, lsum = 0.f;

  const int rowk = h * 32 + l31;
  const uint32_t qglob = (uint32_t)(qt + wq * 32 + l31);
  const uint32_t mrowbase = ((uint32_t)b * 4096u + qglob) * 128u;

  union PU { i32x4 i; bf16x8 bv; };

  for (int kt0 = 0; kt0 < S_LEN; kt0 += 128) {
    // ---- stage K (hi/lo, plain+swizzle) ----
#pragma unroll
    for (int rr = 0; rr < 4; ++rr) {
      int row = rr * 32 + (t >> 4);
      int c   = (t & 15) * 4;
      float4 k4 = *(const float4*)(Kp + (size_t)(kt0 + row) * 64 + c);
      uint32_t u0=f2u(k4.x),u1=f2u(k4.y),u2=f2u(k4.z),u3=f2u(k4.w);
      uint32_t h01=(u1&0xFFFF0000u)|(u0>>16), h23=(u3&0xFFFF0000u)|(u2>>16);
      uint32_t l0=f2u(k4.x-u2f(u0&0xFFFF0000u)), l1=f2u(k4.y-u2f(u1&0xFFFF0000u));
      uint32_t l2=f2u(k4.z-u2f(u2&0xFFFF0000u)), l3=f2u(k4.w-u2f(u3&0xFFFF0000u));
      uint32_t lo01=(l1&0xFFFF0000u)|(l0>>16), lo23=(l3&0xFFFF0000u)|(l2>>16);
      uint32_t off = ((uint32_t)(row*128 + c*2)) ^ ((uint32_t)((row&7)<<4));
      *(i32x2*)(khiB + off) = i32x2{(int)h01,(int)h23};
      *(i32x2*)(kloB + off) = i32x2{(int)lo01,(int)lo23};
    }
    // ---- stage V k-pair-packed: Vt[kp][d] u32 = bf16(V[2kp][d]) | bf16(V[2kp+1][d])<<16 ----
#pragma unroll
    for (int rr2 = 0; rr2 < 2; ++rr2) {
      int kp = rr2 * 32 + (t >> 4);     // 0..63 pair-row
      int c  = (t & 15) * 4;
      const float* va = Vp + (size_t)(kt0 + 2 * kp) * 64 + c;
      float4 v4a = *(const float4*)va;          // row 2kp
      float4 v4b = *(const float4*)(va + 64);   // row 2kp+1
      uint32_t w0, w1, w2, w3;
      asm("v_cvt_pk_bf16_f32 %0, %1, %2" : "=v"(w0) : "v"(v4a.x), "v"(v4b.x));
      asm("v_cvt_pk_bf16_f32 %0, %1, %2" : "=v"(w1) : "v"(v4a.y), "v"(v4b.y));
      asm("v_cvt_pk_bf16_f32 %0, %1, %2" : "=v"(w2) : "v"(v4a.z), "v"(v4b.z));
      asm("v_cvt_pk_bf16_f32 %0, %1, %2" : "=v"(w3) : "v"(v4a.w), "v"(v4b.w));
      *(i32x4*)(vtsB + (uint32_t)(kp * 256 + c * 4)) = i32x4{(int)w0,(int)w1,(int)w2,(int)w3};
    }
    __syncthreads();

    uint32_t mw;
    if constexpr (USE_WS) {
      mw = Mask[mrowbase + (uint32_t)((kt0 + h * 32) >> 5)];
    } else {
      uint32_t fb = (((uint32_t)b*4096u + qglob)*4096u) + (uint32_t)(kt0 + h*32);
      mw = 0u;
      for (uint32_t j = 0; j < 32u; ++j) mw |= (uint32_t)keep_partitionable(fb + j) << j;
    }

    // ---- QK^T: S^T = K * Q^T, 3-pass split bf16 ----
    f32x16 acc;
#pragma unroll
    for (int i = 0; i < 16; ++i) acc[i] = 0.f;
    bf16x8 kfrag[4];
    const uint32_t kswz = (uint32_t)((rowk&7)<<4);
#pragma unroll
    for (int kc = 0; kc < 4; ++kc) {
      uint32_t off = ((uint32_t)(rowk*128 + kc*32 + hi5*16)) ^ kswz;
      kfrag[kc] = *(const bf16x8*)(khiB + off);
    }
#pragma unroll
    for (int kc = 0; kc < 4; ++kc)
      acc = __builtin_amdgcn_mfma_f32_32x32x16_bf16(kfrag[kc], qhi[kc], acc, 0, 0, 0);
#pragma unroll
    for (int kc = 0; kc < 4; ++kc)
      acc = __builtin_amdgcn_mfma_f32_32x32x16_bf16(kfrag[kc], qlo[kc], acc, 0, 0, 0);
#pragma unroll
    for (int kc = 0; kc < 4; ++kc) {
      uint32_t off = ((uint32_t)(rowk*128 + kc*32 + hi5*16)) ^ kswz;
      kfrag[kc] = *(const bf16x8*)(kloB + off);
    }
#pragma unroll
    for (int kc = 0; kc < 4; ++kc)
      acc = __builtin_amdgcn_mfma_f32_32x32x16_bf16(kfrag[kc], qhi[kc], acc, 0, 0, 0);

    // ---- online softmax (lane-local: all 16 regs share q = l31) ----
    float z[16];
#pragma unroll
    for (int i = 0; i < 16; ++i) z[i] = acc[i] * inv_s;
    float tmax = z[0];
#pragma unroll
    for (int i = 1; i < 16; ++i) tmax = fmaxf(tmax, z[i]);
    tmax = fmaxf(tmax, __shfl_xor(tmax, 32));
    float mn = fmaxf(m, tmax);
    if (!__all(mn == m)) {
      float cr = __expf(m - mn);
      m = mn;
      lsum *= cr;
#pragma unroll
      for (int r = 0; r < 16; ++r) {
        int qr = (r & 3) + 8 * (r >> 2) + 4 * hi5;
        float cq = __shfl(cr, qr);
        o0[r] *= cq; o1[r] *= cq;
      }
    }
    float em[16];
#pragma unroll
    for (int r = 0; r < 16; ++r) {
      float e = __expf(z[r] - m);
      lsum += e;                                   // denominator: UNMASKED
      int bit = (r & 3) + 8 * (r >> 2) + 4 * hi5;  // kv-local index
      em[r] = ((mw >> bit) & 1u) ? e : 0.f;
    }

    // ---- P -> A-operand fragments (contiguous k = 8*hi5+j) via cvt_pk + shfl_xor(32) ----
    uint32_t cw[8];
#pragma unroll
    for (int i = 0; i < 8; ++i)
      asm("v_cvt_pk_bf16_f32 %0, %1, %2" : "=v"(cw[i]) : "v"(em[2*i]), "v"(em[2*i+1]));
    uint32_t sx[8];
#pragma unroll
    for (int i = 0; i < 8; ++i) sx[i] = (uint32_t)__shfl_xor((int)cw[i], 32);
    PU pf0, pf1;
    pf0.i = i32x4{ (int)(hi5 ? sx[2] : cw[0]),
                   (int)(hi5 ? sx[3] : cw[1]),
                   (int)(hi5 ? cw[2] : sx[0]),
                   (int)(hi5 ? cw[3] : sx[1]) };
    pf1.i = i32x4{ (int)(hi5 ? sx[6] : cw[4]),
                   (int)(hi5 ? sx[7] : cw[5]),
                   (int)(hi5 ? cw[6] : sx[4]),
                   (int)(hi5 ? cw[7] : sx[5]) };

    // ---- V B-fragments: 4x aligned b32 reads per fragment from pair-packed Vt ----
    PU vf00, vf01, vf10, vf11;
#pragma unroll
    for (int ks = 0; ks < 2; ++ks)
#pragma unroll
      for (int vb = 0; vb < 2; ++vb) {
        int kpb = 16*h + 8*ks + 4*hi5;   // pair-row base; word jj at kpb+jj
        int d   = vb*32 + l31;
        int wds[4];
#pragma unroll
        for (int jj = 0; jj < 4; ++jj)
          wds[jj] = *(const int*)(vtsB + (uint32_t)((kpb + jj) * 256 + d * 4));
        PU tmp; tmp.i = i32x4{wds[0], wds[1], wds[2], wds[3]};
        if (ks == 0 && vb == 0) vf00 = tmp;
        else if (ks == 0 && vb == 1) vf01 = tmp;
        else if (ks == 1 && vb == 0) vf10 = tmp;
        else vf11 = tmp;
      }

    // ---- PV: O = P * V ----
    o0 = __builtin_amdgcn_mfma_f32_32x32x16_bf16(pf0.bv, vf00.bv, o0, 0, 0, 0);
    o0 = __builtin_amdgcn_mfma_f32_32x32x16_bf16(pf1.bv, vf10.bv, o0, 0, 0, 0);
    o1 = __builtin_amdgcn_mfma_f32_32x32x16_bf16(pf0.bv, vf01.bv, o1, 0, 0, 0);
    o1 = __builtin_amdgcn_mfma_f32_32x32x16_bf16(pf1.bv, vf11.bv, o1, 0, 0, 0);
    __syncthreads();
  }

  // ---- merge the 4 kv-quarters per q-group ----
  lsum += __shfl_xor(lsum, 32);
  if (h > 0) {
    if (lane < 32) { sm_ml[wq][h-1][0][l31] = m; sm_ml[wq][h-1][1][l31] = lsum; }
    float* dst = smf + (size_t)(wq * 3 + (h - 1)) * 2048;
#pragma unroll
    for (int r = 0; r < 16; ++r) {
      int qr = (r & 3) + 8 * (r >> 2) + 4 * hi5;
      dst[qr * 64 + l31]      = o0[r];
      dst[qr * 64 + 32 + l31] = o1[r];
    }
  }
  __syncthreads();
  if (h == 0) {
#pragma unroll
    for (int hp = 1; hp < 4; ++hp) {
      float mp = sm_ml[wq][hp-1][0][l31];
      float lp = sm_ml[wq][hp-1][1][l31];
      float mm = fmaxf(m, mp);
      float ca = __expf(m - mm);
      float cb = __expf(mp - mm);
      lsum = lsum * ca + lp * cb;
      m = mm;
      const float* srcp = smf + (size_t)(wq * 3 + (hp - 1)) * 2048;
#pragma unroll
      for (int r = 0; r < 16; ++r) {
        int qr = (r & 3) + 8 * (r >> 2) + 4 * hi5;
        float caq = __shfl(ca, qr);
        float cbq = __shfl(cb, qr);
        o0[r] = o0[r] * caq + srcp[qr * 64 + l31] * cbq;
        o1[r] = o1[r] * caq + srcp[qr * 64 + 32 + l31] * cbq;
      }
    }
    float rinv = 1.0f / (lsum * KEEP_P);
    float* op = Out + ((size_t)b * S_LEN + (size_t)(qt + wq * 32)) * 64;
#pragma unroll
    for (int r = 0; r < 16; ++r) {
      int qr = (r & 3) + 8 * (r >> 2) + 4 * hi5;
      float rq = __shfl(rinv, qr);
      op[(size_t)qr * 64 + l31]      = o0[r] * rq;
      op[(size_t)qr * 64 + 32 + l31] = o1[r] * rq;
    }
  }
}

extern "C" void kernel_launch(void* const* d_in, const int* in_sizes, int n_in,
                              void* d_out, int out_size, void* d_ws, size_t ws_size,
                              hipStream_t stream) {
  (void)in_sizes; (void)n_in; (void)out_size;
  const float* q = (const float*)d_in[0];
  const float* k = (const float*)d_in[1];
  const float* v = (const float*)d_in[2];
  const float* s = (const float*)d_in[3];
  float* out = (float*)d_out;

  const bool use_ws = ws_size >= (size_t)MASK_WORDS * sizeof(uint32_t);
  if (use_ws) {
    uint32_t* mask = (uint32_t*)d_ws;
    maskgen_kernel<<<MASK_WORDS / 256u, 256, 0, stream>>>(mask);  // 8192 blocks
    attn_mfma<true><<<dim3(256), dim3(512), 0, stream>>>(q, k, v, s, mask, out);
  } else {
    attn_mfma<false><<<dim3(256), dim3(512), 0, stream>>>(q, k, v, s, nullptr, out);
  }
}